// Round 5
// baseline (2435.713 us; speedup 1.0000x reference)
//
#include <hip/hip_runtime.h>
#include <hip/hip_bf16.h>
#include <math.h>

// Problem dims (fixed)
#define B   64
#define NN  196
#define HH  512
#define EE  512
#define AA  512
#define VV  20000
#define LL  20

// LDS tile row stride: 32 data ushorts + 8 pad = 40 (80B row; bank advance 20
// dwords, gcd(20,32)=4 -> 16 rows hit 8 distinct 4-bank groups = 2-way, free)
#define LDT 40

typedef __attribute__((ext_vector_type(8))) short bf16x8;
typedef __attribute__((ext_vector_type(4))) float floatx4;

__device__ __forceinline__ float tanh_fast(float x) {
  float e2 = __expf(2.f * x);
  return 1.f - 2.f / (e2 + 1.f);
}
__device__ __forceinline__ float sigmoid_fast(float x) {
  return 1.f / (1.f + __expf(-x));
}
__device__ __forceinline__ float bf2f(unsigned short u) {
  return __uint_as_float(((unsigned)u) << 16);
}
__device__ __forceinline__ unsigned short f2bf(float v) {
  __hip_bfloat16 h = __float2bfloat16(v);
  return *reinterpret_cast<unsigned short*>(&h);
}

// ---------------------------------------------------------------------------
// bf16 MFMA GEMM: C[M,N] = Xb[M,K](bf16) @ Wb[N,K](bf16)^T + bias
// 128x128 tile, BK=32, 256 threads = 4 waves, each wave 64x64 via 16 MFMAs.
// LDS: padded row stride LDT=40 ushorts kills the 8-way ds_read_b128 bank
// conflict (2-way residual is free). NO XOR swizzle (a (row&7)<<3 XOR
// overflows 32-wide rows and aliases rows — round-4 bug).
// gridMX: 0 -> (x=n-tiles, y=m-tiles)
//         2 -> 1D grid, XCD-grouped: all m-blocks of one n-panel go to the
//              same XCD consecutively (panel fetched once per XCD).
// outMode==0: fp32 C[m*ldC+n]
// outMode==1: logits scatter out[b, t+1, n] with m = t*64 + b.
// outMode==2: bf16 store ((ushort*)C)[m*ldC+n]
// outMode==4: C[m*2048+n] = acc + add1[m*2560+512+n] + add2[m*2048+n]
// ---------------------------------------------------------------------------
__global__ __launch_bounds__(256) void gemm_mfma_bt(
    const unsigned short* __restrict__ Xb, const unsigned short* __restrict__ Wb,
    const float* __restrict__ bias, float* __restrict__ C,
    int M, int N, int K, int ldC, int outMode, int gridMX,
    const float* __restrict__ add1, const float* __restrict__ add2) {
  __shared__ unsigned short As[128 * LDT];
  __shared__ unsigned short Bs[128 * LDT];
  const int tid = threadIdx.x;
  const int lane = tid & 63;
  const int l15 = lane & 15;
  const int q = lane >> 4;        // quad 0..3
  const int wv = tid >> 6;        // wave 0..3
  const int wm = (wv >> 1) * 64;  // wave m-offset in tile
  const int wn = (wv & 1) * 64;   // wave n-offset in tile
  int mBase, nBase;
  if (gridMX == 2) {
    const int MT = (M + 127) >> 7, NT = (N + 127) >> 7;
    int wg = blockIdx.x;
    int xcd = wg & 7, idx = wg >> 3;
    int kk = idx / MT, mi = idx - kk * MT;
    int p = kk * 8 + xcd;
    if (p >= NT) return;
    mBase = mi * 128;
    nBase = p * 128;
  } else {
    mBase = blockIdx.y * 128;
    nBase = blockIdx.x * 128;
  }

  const int c0 = tid, c1 = tid + 256;
  const int r0 = c0 >> 2, o0 = (c0 & 3) * 8;
  const int r1 = c1 >> 2, o1 = (c1 & 3) * 8;

  floatx4 zero = {0.f, 0.f, 0.f, 0.f};
  floatx4 acc[4][4];
#pragma unroll
  for (int i = 0; i < 4; ++i)
#pragma unroll
    for (int j = 0; j < 4; ++j) acc[i][j] = zero;

  for (int k0 = 0; k0 < K; k0 += 32) {
    uint4 a0 = *(const uint4*)(Xb + (size_t)(mBase + r0) * K + k0 + o0);
    uint4 a1 = *(const uint4*)(Xb + (size_t)(mBase + r1) * K + k0 + o1);
    uint4 b0 = *(const uint4*)(Wb + (size_t)(nBase + r0) * K + k0 + o0);
    uint4 b1 = *(const uint4*)(Wb + (size_t)(nBase + r1) * K + k0 + o1);
    __syncthreads();
    *(uint4*)&As[r0 * LDT + o0] = a0;
    *(uint4*)&As[r1 * LDT + o1] = a1;
    *(uint4*)&Bs[r0 * LDT + o0] = b0;
    *(uint4*)&Bs[r1 * LDT + o1] = b1;
    __syncthreads();
    bf16x8 af[4], bfv[4];
#pragma unroll
    for (int i = 0; i < 4; ++i)
      af[i] = *(const bf16x8*)&As[(wm + i * 16 + l15) * LDT + q * 8];
#pragma unroll
    for (int j = 0; j < 4; ++j)
      bfv[j] = *(const bf16x8*)&Bs[(wn + j * 16 + l15) * LDT + q * 8];
#pragma unroll
    for (int i = 0; i < 4; ++i)
#pragma unroll
      for (int j = 0; j < 4; ++j)
        acc[i][j] = __builtin_amdgcn_mfma_f32_16x16x32_bf16(af[i], bfv[j],
                                                            acc[i][j], 0, 0, 0);
  }

#pragma unroll
  for (int i = 0; i < 4; ++i) {
#pragma unroll
    for (int j = 0; j < 4; ++j) {
#pragma unroll
      for (int p = 0; p < 4; ++p) {
        int m = mBase + wm + i * 16 + q * 4 + p;
        int n = nBase + wn + j * 16 + l15;
        if (m < M && n < N) {
          float v = acc[i][j][p];
          if (bias) v += bias[n];
          if (outMode == 1) {
            size_t idx = (size_t)(m & 63) * ((size_t)LL * VV) +
                         (size_t)((m >> 6) + 1) * VV + n;
            C[idx] = v;
          } else if (outMode == 2) {
            ((unsigned short*)C)[(size_t)m * ldC + n] = f2bf(v);
          } else if (outMode == 4) {
            C[(size_t)m * 2048 + n] =
                v + add1[(size_t)m * 2560 + 512 + n] + add2[(size_t)m * 2048 + n];
          } else {
            C[(size_t)m * ldC + n] = v;
          }
        }
      }
    }
  }
}

// ---------------------------------------------------------------------------
// gemm_h: fused LSTM-pointwise + h @ [dec_W | W_hh]^T  -> hgd[64][2560] fp32
// Grid = 20 blocks (one 128-wide n-tile each), 256 thr = 4 waves.
// Prologue (redundant per block): h = pointwise(gates_total, c_old); h kept
// in LDS (bf16). hsL rows are 512 ushorts wide, so the (row&7)<<3 XOR swizzle
// IS valid here (stays in-row) and gives 2-way banks. Block 0 also writes
// c_new and hb_row (bf16). GEMM: M=64 rows; wave wv covers n-slice wv*32.
// ---------------------------------------------------------------------------
__global__ __launch_bounds__(256) void gemm_h(
    const float* __restrict__ gt,      // gates_total [64][2048] (unused if first)
    const float* __restrict__ c_old,   // [64][512]
    float* __restrict__ c_new,         // [64][512]
    unsigned short* __restrict__ hb_row,  // bf16 h history slot (or null)
    const unsigned short* __restrict__ Wcatb,  // [2560][512] bf16
    float* __restrict__ hgd,           // [64][2560] out
    int isFirst) {
  __shared__ unsigned short hsL[64 * 512];  // 64KB, XOR-swizzled
  __shared__ unsigned short Bs[128 * LDT];  // 10KB, padded
  const int tid = threadIdx.x;
  const int lane = tid & 63;
  const int l15 = lane & 15;
  const int q = lane >> 4;
  const int wv = tid >> 6;
  const int wn = wv * 32;
  const int nBase = blockIdx.x * 128;

  // ---- pointwise prologue: h -> LDS ----
  if (isFirst) {
    for (int e = tid; e < 16384; e += 256) ((unsigned*)hsL)[e] = 0u;
  } else {
#pragma unroll 4
    for (int it = 0; it < 64; ++it) {
      int e2 = (it * 256 + tid) * 2;
      int b = e2 >> 9, j = e2 & 511;
      const float* g = gt + (size_t)b * 2048 + j;
      float2 gi = *(const float2*)(g);
      float2 gf = *(const float2*)(g + 512);
      float2 gg = *(const float2*)(g + 1024);
      float2 go = *(const float2*)(g + 1536);
      float2 cc = *(const float2*)(c_old + e2);
      float cn0 = sigmoid_fast(gf.x) * cc.x + sigmoid_fast(gi.x) * tanh_fast(gg.x);
      float cn1 = sigmoid_fast(gf.y) * cc.y + sigmoid_fast(gi.y) * tanh_fast(gg.y);
      float hn0 = sigmoid_fast(go.x) * tanh_fast(cn0);
      float hn1 = sigmoid_fast(go.y) * tanh_fast(cn1);
      if (blockIdx.x == 0) {
        *(float2*)(c_new + e2) = make_float2(cn0, cn1);
        unsigned hp = (unsigned)f2bf(hn0) | ((unsigned)f2bf(hn1) << 16);
        *(unsigned*)&hb_row[e2] = hp;
      }
      unsigned hp2 = (unsigned)f2bf(hn0) | ((unsigned)f2bf(hn1) << 16);
      *(unsigned*)&hsL[b * 512 + (j ^ ((b & 7) << 3))] = hp2;
    }
  }

  // ---- staging indices for B ----
  const int c0 = tid, c1 = tid + 256;
  const int r0 = c0 >> 2, o0 = (c0 & 3) * 8;
  const int r1 = c1 >> 2, o1 = (c1 & 3) * 8;
  const int rs = (l15 & 7) << 3;  // hsL read swizzle (valid: 512-wide rows)

  floatx4 zero = {0.f, 0.f, 0.f, 0.f};
  floatx4 acc[4][2];
#pragma unroll
  for (int i = 0; i < 4; ++i)
#pragma unroll
    for (int j = 0; j < 2; ++j) acc[i][j] = zero;

  for (int k0 = 0; k0 < 512; k0 += 32) {
    uint4 b0 = *(const uint4*)(Wcatb + (size_t)(nBase + r0) * 512 + k0 + o0);
    uint4 b1 = *(const uint4*)(Wcatb + (size_t)(nBase + r1) * 512 + k0 + o1);
    __syncthreads();
    *(uint4*)&Bs[r0 * LDT + o0] = b0;
    *(uint4*)&Bs[r1 * LDT + o1] = b1;
    __syncthreads();
    bf16x8 af[4], bfv[2];
#pragma unroll
    for (int i = 0; i < 4; ++i)
      af[i] = *(const bf16x8*)&hsL[(i * 16 + l15) * 512 + ((k0 + q * 8) ^ rs)];
#pragma unroll
    for (int j = 0; j < 2; ++j)
      bfv[j] = *(const bf16x8*)&Bs[(wn + j * 16 + l15) * LDT + q * 8];
#pragma unroll
    for (int i = 0; i < 4; ++i)
#pragma unroll
      for (int j = 0; j < 2; ++j)
        acc[i][j] = __builtin_amdgcn_mfma_f32_16x16x32_bf16(af[i], bfv[j],
                                                            acc[i][j], 0, 0, 0);
  }

#pragma unroll
  for (int i = 0; i < 4; ++i) {
#pragma unroll
    for (int j = 0; j < 2; ++j) {
#pragma unroll
      for (int p = 0; p < 4; ++p) {
        int m = i * 16 + q * 4 + p;               // 0..63
        int n = nBase + wn + j * 16 + l15;        // 0..2559
        hgd[(size_t)m * 2560 + n] = acc[i][j][p];
      }
    }
  }
}

// ---------------------------------------------------------------------------
// fp32 -> bf16 conversion with optional row padding (zero fill) and stride.
// ---------------------------------------------------------------------------
__global__ __launch_bounds__(256) void convert_pad(
    const float* __restrict__ src, unsigned short* __restrict__ dst,
    int srcRows, int dstRows, int srcStride, int colOff) {
  int idx = blockIdx.x * 256 + threadIdx.x;
  if (idx >= dstRows * 512) return;
  int r = idx >> 9, cc = idx & 511;
  float v = (r < srcRows) ? src[(size_t)r * srcStride + colOff + cc] : 0.f;
  dst[idx] = f2bf(v);
}

__global__ __launch_bounds__(256) void bsum_kernel(
    const float* __restrict__ b_ih, const float* __restrict__ b_hh,
    float* __restrict__ bsum) {
  int idx = blockIdx.x * 256 + threadIdx.x;
  if (idx < 2048) bsum[idx] = b_ih[idx] + b_hh[idx];
}

// ---------------------------------------------------------------------------
// Gather embeddings -> bf16, rows m = t*64+b, zero pad rows 1216..1279
// ---------------------------------------------------------------------------
__global__ __launch_bounds__(256) void gather_emb(
    const float* __restrict__ emb, const int* __restrict__ captions,
    unsigned short* __restrict__ embx) {
  int m = blockIdx.x;
  int tid = threadIdx.x;
  if (m >= 1216) {
    embx[(size_t)m * 512 + tid] = 0;
    embx[(size_t)m * 512 + 256 + tid] = 0;
    return;
  }
  int t = m >> 6, b = m & 63;
  int cap = captions[b * LL + t];
#pragma unroll
  for (int i = 0; i < 2; ++i) {
    float v = emb[(size_t)cap * 512 + i * 256 + tid];
    embx[(size_t)m * 512 + i * 256 + tid] = f2bf(v);
  }
}

__global__ __launch_bounds__(256) void zero_t0_kernel(float* __restrict__ out) {
  int idx = blockIdx.x * 256 + threadIdx.x;
  if (idx < B * VV) {
    int b = idx / VV, v = idx % VV;
    out[(size_t)b * ((size_t)LL * VV) + v] = 0.f;
  }
}

// ---------------------------------------------------------------------------
// Attention scores + softmax + context (one block of 512 thr per b).
//   dec[b,:] read from hgd cols 0..511 (+dec_b here)
//   scores_n = tanh(enc_projb[b,n,:] + dec) . eW + eb   (bf16 reads)
//   softmax over N; ctx = attw @ encOutb -> ctxb (bf16)
// ---------------------------------------------------------------------------
__global__ __launch_bounds__(512) void attn_score_ctx(
    const unsigned short* __restrict__ enc_projb,
    const unsigned short* __restrict__ encOutb,
    const float* __restrict__ hgd, const float* __restrict__ dec_b,
    const float* __restrict__ eW, const float* __restrict__ eb,
    unsigned short* __restrict__ ctxb) {
  int b = blockIdx.x;
  int tid = threadIdx.x;
  __shared__ float sw[NN];
  __shared__ float tmp[256];
  __shared__ float cp[1024];

  int wvv = tid >> 6, lane = tid & 63;
  float ew8[8], sd8[8];
  const float* db = hgd + (size_t)b * 2560;
#pragma unroll
  for (int j = 0; j < 8; ++j) {
    ew8[j] = eW[lane * 8 + j];
    sd8[j] = db[lane * 8 + j] + dec_b[lane * 8 + j];
  }
  float eb0 = eb[0];
  for (int n = wvv; n < NN; n += 8) {
    const unsigned short* ep = enc_projb + ((size_t)b * NN + n) * 512 + lane * 8;
    bf16x8 v8 = *(const bf16x8*)ep;
    float a = 0.f;
#pragma unroll
    for (int j = 0; j < 8; ++j)
      a += tanh_fast(bf2f((unsigned short)v8[j]) + sd8[j]) * ew8[j];
#pragma unroll
    for (int off = 32; off; off >>= 1) a += __shfl_down(a, off, 64);
    if (lane == 0) sw[n] = a + eb0;
  }
  __syncthreads();

  // softmax over N
  float v = (tid < NN) ? sw[tid] : -1e30f;
  if (tid < 256) tmp[tid] = v;
  __syncthreads();
  for (int s = 128; s; s >>= 1) {
    if (tid < s) tmp[tid] = fmaxf(tmp[tid], tmp[tid + s]);
    __syncthreads();
  }
  float mx = tmp[0];
  __syncthreads();
  float e = (tid < NN) ? __expf(v - mx) : 0.f;
  if (tid < 256) tmp[tid] = e;
  __syncthreads();
  for (int s = 128; s; s >>= 1) {
    if (tid < s) tmp[tid] += tmp[tid + s];
    __syncthreads();
  }
  float inv = 1.f / tmp[0];
  if (tid < NN) sw[tid] = e * inv;
  __syncthreads();

  // context: bf16 enc_out, uint loads, n split across thread halves
  int half = tid >> 8, hp = tid & 255;
  const unsigned short* eo = encOutb + (size_t)b * NN * 512 + hp * 2;
  float a0 = 0.f, a1 = 0.f;
  int n0 = half * 98;
#pragma unroll 7
  for (int n = n0; n < n0 + 98; ++n) {
    float w = sw[n];
    unsigned u = *(const unsigned*)(eo + (size_t)n * 512);
    a0 += w * __uint_as_float((u & 0xffffu) << 16);
    a1 += w * __uint_as_float((u >> 16) << 16);
  }
  cp[half * 512 + hp * 2] = a0;
  cp[half * 512 + hp * 2 + 1] = a1;
  __syncthreads();
  ctxb[(size_t)b * 512 + tid] = f2bf(cp[tid] + cp[512 + tid]);
}

// ---------------------------------------------------------------------------
// Final h_19 from gates_total -> hb rows 1152..1215 (bf16)
// ---------------------------------------------------------------------------
__global__ __launch_bounds__(256) void final_h(
    const float* __restrict__ gt, const float* __restrict__ c_old,
    unsigned short* __restrict__ hb19) {
  int idx = blockIdx.x * 256 + threadIdx.x;  // 0 .. 64*512
  int b = idx >> 9, j = idx & 511;
  const float* g = gt + (size_t)b * 2048;
  float ig = g[j], fg = g[512 + j], gg = g[1024 + j], og = g[1536 + j];
  float cn = sigmoid_fast(fg) * c_old[idx] + sigmoid_fast(ig) * tanh_fast(gg);
  float hn = sigmoid_fast(og) * tanh_fast(cn);
  hb19[idx] = f2bf(hn);
}

extern "C" void kernel_launch(void* const* d_in, const int* in_sizes, int n_in,
                              void* d_out, int out_size, void* d_ws, size_t ws_size,
                              hipStream_t stream) {
  const float* enc_out  = (const float*)d_in[0];
  const int*   captions = (const int*)d_in[1];
  const float* emb      = (const float*)d_in[2];
  const float* W_ih     = (const float*)d_in[3];
  const float* W_hh     = (const float*)d_in[4];
  const float* b_ih     = (const float*)d_in[5];
  const float* b_hh     = (const float*)d_in[6];
  const float* enc_W    = (const float*)d_in[7];
  const float* enc_b    = (const float*)d_in[8];
  const float* dec_W    = (const float*)d_in[9];
  const float* dec_b    = (const float*)d_in[10];
  const float* energy_W = (const float*)d_in[11];
  const float* energy_b = (const float*)d_in[12];
  const float* fc_W     = (const float*)d_in[13];
  const float* fc_b     = (const float*)d_in[14];
  float* out = (float*)d_out;

  // Workspace layout
  float* ws = (float*)d_ws;
  float* c2          = ws;                                  // 2 * 64*512
  float* gates_all   = c2 + 2 * 32768;                      // 19*64*2048
  float* gates_total = gates_all + (size_t)19 * 131072;     // 64*2048
  float* hgd         = gates_total + 131072;                // 2 * 64*2560
  float* bsum        = hgd + 2 * 163840;                    // 2048
  unsigned short* enc_projb = (unsigned short*)(bsum + 2048); // 12544*512
  unsigned short* fcWb    = enc_projb + (size_t)12544 * 512;  // 20096*512
  unsigned short* encWb   = fcWb + (size_t)20096 * 512;       // 512*512
  unsigned short* encOutb = encWb + (size_t)512 * 512;        // 12544*512
  unsigned short* Wb0b    = encOutb + (size_t)12544 * 512;    // 2048*512
  unsigned short* Wicb    = Wb0b + (size_t)2048 * 512;        // 2048*512
  unsigned short* Wcatb   = Wicb + (size_t)2048 * 512;        // 2560*512
  unsigned short* embxb   = Wcatb + (size_t)2560 * 512;       // 1280*512
  unsigned short* hb      = embxb + (size_t)1280 * 512;       // 1280*512
  unsigned short* ctxb    = hb + (size_t)1280 * 512;          // 128*512

  hipMemsetAsync(c2, 0, 32768 * sizeof(float), stream);     // c_0 = 0 (buf 0)
  hipMemsetAsync(hb + (size_t)1216 * 512, 0,
                 (size_t)64 * 512 * sizeof(unsigned short), stream);
  hipMemsetAsync(ctxb + (size_t)64 * 512, 0,
                 (size_t)64 * 512 * sizeof(unsigned short), stream);
  zero_t0_kernel<<<(B * VV + 255) / 256, 256, 0, stream>>>(out);

  bsum_kernel<<<8, 256, 0, stream>>>(b_ih, b_hh, bsum);

  convert_pad<<<(20096 * 512) / 256, 256, 0, stream>>>(fc_W, fcWb, 20000, 20096, 512, 0);
  convert_pad<<<(512 * 512) / 256, 256, 0, stream>>>(enc_W, encWb, 512, 512, 512, 0);
  convert_pad<<<(12544 * 512) / 256, 256, 0, stream>>>(enc_out, encOutb, 12544, 12544, 512, 0);
  convert_pad<<<(2048 * 512) / 256, 256, 0, stream>>>(W_ih, Wb0b, 2048, 2048, 1024, 0);
  convert_pad<<<(2048 * 512) / 256, 256, 0, stream>>>(W_ih, Wicb, 2048, 2048, 1024, 512);
  convert_pad<<<(512 * 512) / 256, 256, 0, stream>>>(dec_W, Wcatb, 512, 512, 512, 0);
  convert_pad<<<(2048 * 512) / 256, 256, 0, stream>>>(W_hh, Wcatb + (size_t)512 * 512,
                                                      2048, 2048, 512, 0);

  gather_emb<<<1280, 256, 0, stream>>>(emb, captions, embxb);

  // gates_x[t*64+b, :] = embx @ W_ih[:, :512]^T + (b_ih + b_hh)   [MFMA]
  gemm_mfma_bt<<<dim3(16, 10), 256, 0, stream>>>(
      embxb, Wb0b, bsum, gates_all, 1216, 2048, 512, 2048, 0, 0, nullptr, nullptr);

  // enc_projb (bf16) = enc_out @ enc_W^T + enc_b   [MFMA, bf16 store]
  gemm_mfma_bt<<<dim3(4, 98), 256, 0, stream>>>(
      encOutb, encWb, enc_b, (float*)enc_projb, 12544, 512, 512, 512, 2, 0,
      nullptr, nullptr);

  for (int s = 0; s < LL - 1; ++s) {
    float* hgd_cur = hgd + (size_t)(s & 1) * 163840;
    // 1) h_s = pointwise(gates_total, c_{s-1}); hgd = h @ [dec_W|W_hh]^T
    gemm_h<<<20, 256, 0, stream>>>(
        gates_total, c2 + (size_t)((s + 1) & 1) * 32768,
        c2 + (size_t)(s & 1) * 32768,
        s ? hb + (size_t)(s - 1) * 32768 : nullptr, Wcatb, hgd_cur,
        s == 0 ? 1 : 0);

    // 2) scores + softmax + context -> ctxb (bf16)
    attn_score_ctx<<<B, 512, 0, stream>>>(enc_projb, encOutb, hgd_cur, dec_b,
                                          energy_W, energy_b, ctxb);

    // 3) gates_total = ctx @ W_ic^T + hg + gx[s]   [MFMA]
    gemm_mfma_bt<<<dim3(16, 1), 256, 0, stream>>>(
        ctxb, Wicb, nullptr, gates_total, 64, 2048, 512, 2048, 4, 0, hgd_cur,
        gates_all + (size_t)s * 131072);
  }

  // h_19 -> hb rows 1152..1215   (c_18 lives in c2 buffer 0)
  final_h<<<(B * HH) / 256, 256, 0, stream>>>(gates_total, c2,
                                              hb + (size_t)1152 * 512);

  // Batched logits: out[b, t+1, :] = h @ fc_W^T + fc_b  [MFMA, XCD-grouped]
  gemm_mfma_bt<<<1600, 256, 0, stream>>>(
      hb, fcWb, fc_b, out, 1216, 20000, 512, 0, 1, 2, nullptr, nullptr);
}

// Round 6
// 1677.619 us; speedup vs baseline: 1.4519x; 1.4519x over previous
//
#include <hip/hip_runtime.h>
#include <hip/hip_bf16.h>
#include <math.h>

// Problem dims (fixed)
#define B   64
#define NN  196
#define HH  512
#define EE  512
#define AA  512
#define VV  20000
#define LL  20

typedef __attribute__((ext_vector_type(8))) short bf16x8;
typedef __attribute__((ext_vector_type(4))) float floatx4;

__device__ __forceinline__ float tanh_fast(float x) {
  float e2 = __expf(2.f * x);
  return 1.f - 2.f / (e2 + 1.f);
}
__device__ __forceinline__ float sigmoid_fast(float x) {
  return 1.f / (1.f + __expf(-x));
}
__device__ __forceinline__ float bf2f(unsigned short u) {
  return __uint_as_float(((unsigned)u) << 16);
}
__device__ __forceinline__ unsigned short f2bf(float v) {
  __hip_bfloat16 h = __float2bfloat16(v);
  return *reinterpret_cast<unsigned short*>(&h);
}

// Chunk-XOR LDS slot for a 16B chunk (row, chunkcol q4): bijective per row,
// and both staging writes (8 consecutive lanes = 8 distinct 4-bank groups)
// and ds_read_b128 fragment reads (8 consecutive lanes = rows r..r+7 at fixed
// q -> (r&1, q^((r>>1)&3)) all distinct) are bank-conflict-free.
__device__ __forceinline__ int ldsw(int row, int q4) {
  return (row * 4 + (q4 ^ ((row >> 1) & 3))) * 8;
}

// ---------------------------------------------------------------------------
// bf16 MFMA GEMM: C[M,N] = Xb[M,K](bf16, row stride lda) @ Wb[N,K](bf16)^T + b
// 128x128 tile, BK=32, 256 threads = 4 waves, each wave 64x64 via 16 MFMAs.
// LDS chunk-XOR layout (see ldsw) -> conflict-free staging + fragment reads.
// gridMX: 0 -> (x=n-tiles, y=m-tiles)
//         2 -> 1D grid, XCD-grouped: all m-blocks of one n-panel on one XCD
//              consecutively (B-panel fetched ~once per XCD; proven: FETCH
//              88MB -> 24MB on logits).
// outMode==0: fp32 C[m*ldC+n];  ==1: logits scatter out[b,t+1,n], m=t*64+b;
// ==2: bf16 store ((ushort*)C)[m*ldC+n]
// A rows beyond M may be read (must be allocated); outputs masked.
// ---------------------------------------------------------------------------
__global__ __launch_bounds__(256) void gemm_mfma_bt(
    const unsigned short* __restrict__ Xb, const unsigned short* __restrict__ Wb,
    const float* __restrict__ bias, float* __restrict__ C,
    int M, int N, int K, int lda, int ldC, int outMode, int gridMX) {
  __shared__ unsigned short As[128 * 32];
  __shared__ unsigned short Bs[128 * 32];
  const int tid = threadIdx.x;
  const int lane = tid & 63;
  const int l15 = lane & 15;
  const int q = lane >> 4;        // quad 0..3 (16B chunk col in K-slice)
  const int wv = tid >> 6;        // wave 0..3
  const int wm = (wv >> 1) * 64;  // wave m-offset in tile
  const int wn = (wv & 1) * 64;   // wave n-offset in tile
  int mBase, nBase;
  if (gridMX == 2) {
    const int MT = (M + 127) >> 7, NT = (N + 127) >> 7;
    int wg = blockIdx.x;
    int xcd = wg & 7, idx = wg >> 3;
    int kk = idx / MT, mi = idx - kk * MT;
    int p = kk * 8 + xcd;
    if (p >= NT) return;
    mBase = mi * 128;
    nBase = p * 128;
  } else {
    mBase = blockIdx.y * 128;
    nBase = blockIdx.x * 128;
  }

  // staging: 512 chunks of 16B per tile; thread stages chunks tid, tid+256
  const int c0 = tid, c1 = tid + 256;
  const int r0 = c0 >> 2, q0 = c0 & 3;
  const int r1 = c1 >> 2, q1 = c1 & 3;
  const int s0 = ldsw(r0, q0), s1 = ldsw(r1, q1);

  floatx4 zero = {0.f, 0.f, 0.f, 0.f};
  floatx4 acc[4][4];
#pragma unroll
  for (int i = 0; i < 4; ++i)
#pragma unroll
    for (int j = 0; j < 4; ++j) acc[i][j] = zero;

  for (int k0 = 0; k0 < K; k0 += 32) {
    uint4 a0 = *(const uint4*)(Xb + (size_t)(mBase + r0) * lda + k0 + q0 * 8);
    uint4 a1 = *(const uint4*)(Xb + (size_t)(mBase + r1) * lda + k0 + q1 * 8);
    uint4 b0 = *(const uint4*)(Wb + (size_t)(nBase + r0) * K + k0 + q0 * 8);
    uint4 b1 = *(const uint4*)(Wb + (size_t)(nBase + r1) * K + k0 + q1 * 8);
    __syncthreads();
    *(uint4*)&As[s0] = a0;
    *(uint4*)&As[s1] = a1;
    *(uint4*)&Bs[s0] = b0;
    *(uint4*)&Bs[s1] = b1;
    __syncthreads();
    bf16x8 af[4], bfv[4];
#pragma unroll
    for (int i = 0; i < 4; ++i)
      af[i] = *(const bf16x8*)&As[ldsw(wm + i * 16 + l15, q)];
#pragma unroll
    for (int j = 0; j < 4; ++j)
      bfv[j] = *(const bf16x8*)&Bs[ldsw(wn + j * 16 + l15, q)];
#pragma unroll
    for (int i = 0; i < 4; ++i)
#pragma unroll
      for (int j = 0; j < 4; ++j)
        acc[i][j] = __builtin_amdgcn_mfma_f32_16x16x32_bf16(af[i], bfv[j],
                                                            acc[i][j], 0, 0, 0);
  }

#pragma unroll
  for (int i = 0; i < 4; ++i) {
#pragma unroll
    for (int j = 0; j < 4; ++j) {
#pragma unroll
      for (int p = 0; p < 4; ++p) {
        int m = mBase + wm + i * 16 + q * 4 + p;
        int n = nBase + wn + j * 16 + l15;
        if (m < M && n < N) {
          float v = acc[i][j][p];
          if (bias) v += bias[n];
          if (outMode == 1) {
            size_t idx = (size_t)(m & 63) * ((size_t)LL * VV) +
                         (size_t)((m >> 6) + 1) * VV + n;
            C[idx] = v;
          } else if (outMode == 2) {
            ((unsigned short*)C)[(size_t)m * ldC + n] = f2bf(v);
          } else {
            C[(size_t)m * ldC + n] = v;
          }
        }
      }
    }
  }
}

// ---------------------------------------------------------------------------
// gemm_gates: gates = xcat_r[64][1024](bf16) @ Wgi[2048][1024](bf16)^T + gx,
// with gate-INTERLEAVED column order n' = 4j+g (g: 0=i,1=f,2=g,3=o), then the
// LSTM pointwise fused in the epilogue (each block owns complete i/f/g/o
// quads for j in [nBase/4, nBase/4+32)).
// Grid = 16 blocks x 256 thr (4 waves; wave wv covers n-slice wv*32).
// Writes: c (in place), h -> xcat_w h-half (bf16) + hb_slot (bf16).
// ---------------------------------------------------------------------------
__global__ __launch_bounds__(256) void gemm_gates(
    const unsigned short* __restrict__ xcat_r,  // [128][1024] bf16
    const unsigned short* __restrict__ Wgi,     // [2048][1024] bf16 interleaved
    const float* __restrict__ gx,               // [64][2048] interleaved
    float* __restrict__ c,                      // [64][512]
    unsigned short* __restrict__ xcat_w,        // [128][1024] bf16
    unsigned short* __restrict__ hb_slot) {     // [64][512] bf16
  __shared__ unsigned short As[64 * 32];
  __shared__ unsigned short Bs[128 * 32];
  __shared__ float gbuf[64][132];
  const int tid = threadIdx.x;
  const int lane = tid & 63;
  const int l15 = lane & 15;
  const int q = lane >> 4;
  const int wv = tid >> 6;
  const int wn = wv * 32;
  const int nBase = blockIdx.x * 128;

  // A: 256 chunks (64 rows x 4), one per thread. B: 512 chunks, two per thread.
  const int ra = tid >> 2, qa = tid & 3;
  const int sa = ldsw(ra, qa);
  const int c0 = tid, c1 = tid + 256;
  const int rb0 = c0 >> 2, qb0 = c0 & 3;
  const int rb1 = c1 >> 2, qb1 = c1 & 3;
  const int sb0 = ldsw(rb0, qb0), sb1 = ldsw(rb1, qb1);

  floatx4 zero = {0.f, 0.f, 0.f, 0.f};
  floatx4 acc[4][2];
#pragma unroll
  for (int i = 0; i < 4; ++i)
#pragma unroll
    for (int j = 0; j < 2; ++j) acc[i][j] = zero;

  for (int k0 = 0; k0 < 1024; k0 += 32) {
    uint4 a0 = *(const uint4*)(xcat_r + (size_t)ra * 1024 + k0 + qa * 8);
    uint4 b0 = *(const uint4*)(Wgi + (size_t)(nBase + rb0) * 1024 + k0 + qb0 * 8);
    uint4 b1 = *(const uint4*)(Wgi + (size_t)(nBase + rb1) * 1024 + k0 + qb1 * 8);
    __syncthreads();
    *(uint4*)&As[sa] = a0;
    *(uint4*)&Bs[sb0] = b0;
    *(uint4*)&Bs[sb1] = b1;
    __syncthreads();
    bf16x8 af[4], bfv[2];
#pragma unroll
    for (int i = 0; i < 4; ++i)
      af[i] = *(const bf16x8*)&As[ldsw(i * 16 + l15, q)];
#pragma unroll
    for (int j = 0; j < 2; ++j)
      bfv[j] = *(const bf16x8*)&Bs[ldsw(wn + j * 16 + l15, q)];
#pragma unroll
    for (int i = 0; i < 4; ++i)
#pragma unroll
      for (int j = 0; j < 2; ++j)
        acc[i][j] = __builtin_amdgcn_mfma_f32_16x16x32_bf16(af[i], bfv[j],
                                                            acc[i][j], 0, 0, 0);
  }

  // acc -> gbuf[m][n]  (m=0..63 local rows, n=0..127 local interleaved cols)
#pragma unroll
  for (int i = 0; i < 4; ++i)
#pragma unroll
    for (int j = 0; j < 2; ++j)
#pragma unroll
      for (int p = 0; p < 4; ++p)
        gbuf[i * 16 + q * 4 + p][wn + j * 16 + l15] = acc[i][j][p];
  __syncthreads();

  // Pointwise: 2048 (b, jl) items, 8 per thread.
#pragma unroll
  for (int it = 0; it < 8; ++it) {
    int e = it * 256 + tid;
    int b = e >> 5, jl = e & 31;
    float4 gv = *(float4*)&gbuf[b][jl * 4];
    float4 gxv = *(const float4*)(gx + (size_t)b * 2048 + nBase + jl * 4);
    float ig = gv.x + gxv.x, fg = gv.y + gxv.y;
    float gg = gv.z + gxv.z, og = gv.w + gxv.w;
    int jg = (nBase >> 2) + jl;
    float cv = c[b * 512 + jg];
    float cn = sigmoid_fast(fg) * cv + sigmoid_fast(ig) * tanh_fast(gg);
    float hn = sigmoid_fast(og) * tanh_fast(cn);
    c[b * 512 + jg] = cn;
    unsigned short hbf = f2bf(hn);
    xcat_w[(size_t)b * 1024 + jg] = hbf;
    hb_slot[(size_t)b * 512 + jg] = hbf;
  }
}

// ---------------------------------------------------------------------------
// fp32 -> bf16 conversion with optional row padding (zero fill) and stride.
// ---------------------------------------------------------------------------
__global__ __launch_bounds__(256) void convert_pad(
    const float* __restrict__ src, unsigned short* __restrict__ dst,
    int srcRows, int dstRows, int srcStride, int colOff) {
  int idx = blockIdx.x * 256 + threadIdx.x;
  if (idx >= dstRows * 512) return;
  int r = idx >> 9, cc = idx & 511;
  float v = (r < srcRows) ? src[(size_t)r * srcStride + colOff + cc] : 0.f;
  dst[idx] = f2bf(v);
}

// ---------------------------------------------------------------------------
// Pack gate-interleaved weights (n' = 4j+g -> original row g*512+j):
//  Wb0i[2048][512]  = W_ih[row][0:512]          (bf16)
//  Wgi [2048][1024] = [W_hh[row] | W_ih[row][512:1024]]  (bf16)
//  bsumi[2048]      = b_ih[row] + b_hh[row]
// ---------------------------------------------------------------------------
__global__ __launch_bounds__(256) void build_weights_i(
    const float* __restrict__ W_ih, const float* __restrict__ W_hh,
    const float* __restrict__ b_ih, const float* __restrict__ b_hh,
    unsigned short* __restrict__ Wb0i, unsigned short* __restrict__ Wgi,
    float* __restrict__ bsumi) {
  int idx = blockIdx.x * 256 + threadIdx.x;
  if (idx < 2048 * 1024) {
    int np = idx >> 10, k = idx & 1023;
    int row = (np & 3) * 512 + (np >> 2);
    float v = (k < 512) ? W_hh[(size_t)row * 512 + k]
                        : W_ih[(size_t)row * 1024 + 512 + (k - 512)];
    Wgi[idx] = f2bf(v);
  }
  if (idx < 2048 * 512) {
    int np = idx >> 9, k = idx & 511;
    int row = (np & 3) * 512 + (np >> 2);
    Wb0i[idx] = f2bf(W_ih[(size_t)row * 1024 + k]);
  }
  if (idx < 2048) {
    int row = (idx & 3) * 512 + (idx >> 2);
    bsumi[idx] = b_ih[row] + b_hh[row];
  }
}

// ---------------------------------------------------------------------------
// Gather embeddings -> bf16, rows m = t*64+b, zero pad rows 1216..1279
// ---------------------------------------------------------------------------
__global__ __launch_bounds__(256) void gather_emb(
    const float* __restrict__ emb, const int* __restrict__ captions,
    unsigned short* __restrict__ embx) {
  int m = blockIdx.x;
  int tid = threadIdx.x;
  if (m >= 1216) {
    embx[(size_t)m * 512 + tid] = 0;
    embx[(size_t)m * 512 + 256 + tid] = 0;
    return;
  }
  int t = m >> 6, b = m & 63;
  int cap = captions[b * LL + t];
#pragma unroll
  for (int i = 0; i < 2; ++i) {
    float v = emb[(size_t)cap * 512 + i * 256 + tid];
    embx[(size_t)m * 512 + i * 256 + tid] = f2bf(v);
  }
}

__global__ __launch_bounds__(256) void zero_t0_kernel(float* __restrict__ out) {
  int idx = blockIdx.x * 256 + threadIdx.x;
  if (idx < B * VV) {
    int b = idx / VV, v = idx % VV;
    out[(size_t)b * ((size_t)LL * VV) + v] = 0.f;
  }
}

// ---------------------------------------------------------------------------
// Attention scores + softmax + context (one block of 512 thr per b).
//   scores_n = tanh(enc_projb[b,n,:] + dec_buf[b,:]) . eW + eb  (bf16 reads)
//   softmax over N; ctx = attw @ encOutb -> xcat ctx-half (bf16)
// ---------------------------------------------------------------------------
__global__ __launch_bounds__(512) void attn_score_ctx(
    const unsigned short* __restrict__ enc_projb,
    const unsigned short* __restrict__ encOutb,
    const float* __restrict__ dec_buf, const float* __restrict__ eW,
    const float* __restrict__ eb, unsigned short* __restrict__ xcat_cur) {
  int b = blockIdx.x;
  int tid = threadIdx.x;
  __shared__ float sw[NN];
  __shared__ float tmp[256];
  __shared__ float cp[1024];

  int wvv = tid >> 6, lane = tid & 63;
  float ew8[8], sd8[8];
  const float* db = dec_buf + (size_t)b * 512;
#pragma unroll
  for (int j = 0; j < 8; ++j) {
    ew8[j] = eW[lane * 8 + j];
    sd8[j] = db[lane * 8 + j];
  }
  float eb0 = eb[0];
  for (int n = wvv; n < NN; n += 8) {
    const unsigned short* ep = enc_projb + ((size_t)b * NN + n) * 512 + lane * 8;
    bf16x8 v8 = *(const bf16x8*)ep;
    float a = 0.f;
#pragma unroll
    for (int j = 0; j < 8; ++j)
      a += tanh_fast(bf2f((unsigned short)v8[j]) + sd8[j]) * ew8[j];
#pragma unroll
    for (int off = 32; off; off >>= 1) a += __shfl_down(a, off, 64);
    if (lane == 0) sw[n] = a + eb0;
  }
  __syncthreads();

  // softmax over N
  float v = (tid < NN) ? sw[tid] : -1e30f;
  if (tid < 256) tmp[tid] = v;
  __syncthreads();
  for (int s = 128; s; s >>= 1) {
    if (tid < s) tmp[tid] = fmaxf(tmp[tid], tmp[tid + s]);
    __syncthreads();
  }
  float mx = tmp[0];
  __syncthreads();
  float e = (tid < NN) ? __expf(v - mx) : 0.f;
  if (tid < 256) tmp[tid] = e;
  __syncthreads();
  for (int s = 128; s; s >>= 1) {
    if (tid < s) tmp[tid] += tmp[tid + s];
    __syncthreads();
  }
  float inv = 1.f / tmp[0];
  if (tid < NN) sw[tid] = e * inv;
  __syncthreads();

  // context: bf16 enc_out, uint loads, n split across thread halves
  int half = tid >> 8, hp = tid & 255;
  const unsigned short* eo = encOutb + (size_t)b * NN * 512 + hp * 2;
  float a0 = 0.f, a1 = 0.f;
  int n0 = half * 98;
#pragma unroll 7
  for (int n = n0; n < n0 + 98; ++n) {
    float w = sw[n];
    unsigned u = *(const unsigned*)(eo + (size_t)n * 512);
    a0 += w * __uint_as_float((u & 0xffffu) << 16);
    a1 += w * __uint_as_float((u >> 16) << 16);
  }
  cp[half * 512 + hp * 2] = a0;
  cp[half * 512 + hp * 2 + 1] = a1;
  __syncthreads();
  xcat_cur[(size_t)b * 1024 + 512 + tid] = f2bf(cp[tid] + cp[512 + tid]);
}

extern "C" void kernel_launch(void* const* d_in, const int* in_sizes, int n_in,
                              void* d_out, int out_size, void* d_ws, size_t ws_size,
                              hipStream_t stream) {
  const float* enc_out  = (const float*)d_in[0];
  const int*   captions = (const int*)d_in[1];
  const float* emb      = (const float*)d_in[2];
  const float* W_ih     = (const float*)d_in[3];
  const float* W_hh     = (const float*)d_in[4];
  const float* b_ih     = (const float*)d_in[5];
  const float* b_hh     = (const float*)d_in[6];
  const float* enc_W    = (const float*)d_in[7];
  const float* enc_b    = (const float*)d_in[8];
  const float* dec_W    = (const float*)d_in[9];
  const float* dec_b    = (const float*)d_in[10];
  const float* energy_W = (const float*)d_in[11];
  const float* energy_b = (const float*)d_in[12];
  const float* fc_W     = (const float*)d_in[13];
  const float* fc_b     = (const float*)d_in[14];
  float* out = (float*)d_out;

  // Workspace layout
  float* ws = (float*)d_ws;
  float* c          = ws;                                   // 64*512
  float* dec_buf    = c + 32768;                            // 64*512
  float* gates_all  = dec_buf + 32768;                      // 19*64*2048 (interleaved)
  float* bsumi      = gates_all + (size_t)19 * 131072;      // 2048
  unsigned short* enc_projb = (unsigned short*)(bsumi + 2048); // 12544*512
  unsigned short* fcWb    = enc_projb + (size_t)12544 * 512;   // 20096*512
  unsigned short* encWb   = fcWb + (size_t)20096 * 512;        // 512*512
  unsigned short* encOutb = encWb + (size_t)512 * 512;         // 12544*512
  unsigned short* Wb0i    = encOutb + (size_t)12544 * 512;     // 2048*512
  unsigned short* Wgi     = Wb0i + (size_t)2048 * 512;         // 2048*1024
  unsigned short* dec_Wb  = Wgi + (size_t)2048 * 1024;         // 512*512
  unsigned short* embxb   = dec_Wb + (size_t)512 * 512;        // 1280*512
  unsigned short* hb      = embxb + (size_t)1280 * 512;        // 1280*512
  unsigned short* xcat2   = hb + (size_t)1280 * 512;           // 2*128*1024

  hipMemsetAsync(c, 0, 32768 * sizeof(float), stream);
  hipMemsetAsync(xcat2, 0, 2 * 128 * 1024 * sizeof(unsigned short), stream);
  hipMemsetAsync(hb + (size_t)1216 * 512, 0,
                 (size_t)64 * 512 * sizeof(unsigned short), stream);
  zero_t0_kernel<<<(B * VV + 255) / 256, 256, 0, stream>>>(out);

  build_weights_i<<<(2048 * 1024) / 256, 256, 0, stream>>>(
      W_ih, W_hh, b_ih, b_hh, Wb0i, Wgi, bsumi);

  convert_pad<<<(20096 * 512) / 256, 256, 0, stream>>>(fc_W, fcWb, 20000, 20096, 512, 0);
  convert_pad<<<(512 * 512) / 256, 256, 0, stream>>>(enc_W, encWb, 512, 512, 512, 0);
  convert_pad<<<(12544 * 512) / 256, 256, 0, stream>>>(enc_out, encOutb, 12544, 12544, 512, 0);
  convert_pad<<<(512 * 512) / 256, 256, 0, stream>>>(dec_W, dec_Wb, 512, 512, 512, 0);

  gather_emb<<<1280, 256, 0, stream>>>(emb, captions, embxb);

  // gates_x (interleaved) = embx @ Wb0i^T + bsumi   [MFMA]
  gemm_mfma_bt<<<dim3(16, 10), 256, 0, stream>>>(
      embxb, Wb0i, bsumi, gates_all, 1216, 2048, 512, 512, 2048, 0, 0);

  // enc_projb (bf16) = enc_out @ enc_W^T + enc_b   [MFMA, bf16 store]
  gemm_mfma_bt<<<dim3(4, 98), 256, 0, stream>>>(
      encOutb, encWb, enc_b, (float*)enc_projb, 12544, 512, 512, 512, 512, 2, 0);

  for (int s = 0; s < LL - 1; ++s) {
    unsigned short* xcur = xcat2 + (size_t)(s & 1) * 131072;
    unsigned short* xnxt = xcat2 + (size_t)((s + 1) & 1) * 131072;

    // 1) dec = h_s @ dec_W^T + dec_b   [MFMA, 4 blocks; A rows 64..127 zero]
    gemm_mfma_bt<<<dim3(4, 1), 256, 0, stream>>>(
        xcur, dec_Wb, dec_b, dec_buf, 64, 512, 512, 1024, 512, 0, 0);

    // 2) scores + softmax + context -> xcur ctx-half (bf16)
    attn_score_ctx<<<B, 512, 0, stream>>>(enc_projb, encOutb, dec_buf,
                                          energy_W, energy_b, xcur);

    // 3) gates (interleaved) + fused pointwise -> c, h_{s+1} -> xnxt + hb[s]
    gemm_gates<<<16, 256, 0, stream>>>(xcur, Wgi,
                                       gates_all + (size_t)s * 131072, c, xnxt,
                                       hb + (size_t)s * 32768);
  }

  // Batched logits: out[b, t+1, :] = h @ fc_W^T + fc_b  [MFMA, XCD-grouped]
  gemm_mfma_bt<<<1600, 256, 0, stream>>>(
      hb, fcWb, fc_b, out, 1216, 20000, 512, 512, 0, 1, 2);
}